// Round 1
// baseline (490.380 us; speedup 1.0000x reference)
//
#include <hip/hip_runtime.h>
#include <hip/hip_bf16.h>
#include <cstddef>

// MultiHeadedCrossAttention, Round 5.
// B=2, I=2048, J=16, NK=2048, D_MODEL=256, D_HIDDEN=512, H=8, D_K=64.
//
// R4 counters: fused_mfma MfmaUtil 15%, VALUBusy 15%, Occ 23%, HBM 6.7% ->
// latency-bound, phase-serialized. R5 changes:
//  * fused: eliminate pos->LDS staging. A-frags are 8 consecutive floats of a
//    pos row -> load 2x float4 directly from global inside the k-loop with a
//    1-deep explicit prefetch; convert via (__bf16) casts (v_cvt_pk_bf16_f32,
//    RNE == f2bf bit-exact for normal inputs). Removes the serial staging
//    phase + 2 barriers; pos tile (128 KB) is L1/L2-hot so the 4x per-wave
//    re-read does not raise HBM fetch. LDS (64 KB) now holds only the hidden
//    frags (stage-2 A operands) -- unchanged size, 2 blocks/CU.
//  * pre: drop the Xs LDS staging (block-uniform broadcast ds_read_b128 was
//    ~2.1M LDS instrs = LDS-pipe bound). Read q/k rows directly from global
//    with uniform addresses (compiler scalarizes to s_load / L1 broadcast).
//    LDS -> 0, staging barrier gone.

#define B_  2
#define I_  2048
#define J_  16
#define NK_ 2048
#define DM  256
#define DH  512
#define H_  8
#define DK  64
#define G_  4    // i's per fused block

typedef __attribute__((ext_vector_type(8))) __bf16 bf16x8;
typedef __attribute__((ext_vector_type(4))) float f32x4;
typedef __attribute__((ext_vector_type(8))) unsigned short ushort8;

__device__ inline unsigned short f2bf(float f) {   // RNE float->bf16
  unsigned int u = __builtin_bit_cast(unsigned int, f);
  u += 0x7FFFu + ((u >> 16) & 1u);
  return (unsigned short)(u >> 16);
}

// 8x f32 -> bf16x8 via native converts (compiler emits v_cvt_pk_bf16_f32).
__device__ inline bf16x8 cvt8(float4 a, float4 b) {
  bf16x8 r;
  r[0] = (__bf16)a.x; r[1] = (__bf16)a.y; r[2] = (__bf16)a.z; r[3] = (__bf16)a.w;
  r[4] = (__bf16)b.x; r[5] = (__bf16)b.y; r[6] = (__bf16)b.z; r[7] = (__bf16)b.w;
  return r;
}

// ---------------------------------------------------------------------------
// Pre-kernel bodies
// ---------------------------------------------------------------------------

// Weight pre-swizzle: W (512 x N f32 row-major) -> bf16 B-frags. (R2-verbatim)
// Frag (nt, ks): lane l holds B[k = ks*32 + (l>>4)*8 + j][n = nt*16 + (l&15)],
// j=0..7, 16B-contiguous at Wf[((nt*16+ks)*64 + l)*8].
template<int N>
__device__ void swz_body(const float* __restrict__ W,
                         unsigned short* __restrict__ Wf, int bid, int t)
{
  const int u  = bid * 256 + t;
  const int l  = u & 63;
  const int fi = u >> 6;
  const int ks = fi & 15;
  const int nt = fi >> 4;
  const int n  = nt * 16 + (l & 15);
  const int k0 = ks * 32 + (l >> 4) * 8;
  unsigned short tmp[8];
  #pragma unroll
  for (int j = 0; j < 8; ++j) tmp[j] = f2bf(W[(size_t)(k0 + j) * N + n]);
  *(ushort8*)&Wf[(size_t)u * 8] = *(const ushort8*)tmp;
}

// Y = X @ W, X: (rows, 256) f32. X rows read with BLOCK-UNIFORM addresses
// directly from global (scalarizable) -- no LDS staging, no barrier.
template<int N, int CPT>
__device__ void proj_body(const float* __restrict__ X,
                          const float* __restrict__ W,
                          float* __restrict__ Y, int bid, int t)
{
  const int row0 = bid * 8;

  float acc[8][CPT];
  #pragma unroll
  for (int r = 0; r < 8; ++r)
    #pragma unroll
    for (int u = 0; u < CPT; ++u) acc[r][u] = 0.f;

  const int c0 = t * CPT;
  #pragma unroll 2
  for (int k = 0; k < DM; k += 4) {
    float4 xv[8];
    #pragma unroll
    for (int r = 0; r < 8; ++r)
      xv[r] = *(const float4*)&X[(size_t)(row0 + r) * DM + k];   // uniform addr
    #pragma unroll
    for (int kk = 0; kk < 4; ++kk) {
      float w[CPT];
      if constexpr (CPT == 2) {
        const float2 wv = *(const float2*)&W[(size_t)(k + kk) * N + c0];
        w[0] = wv.x; w[1] = wv.y;
      } else {
        const float4 wv = *(const float4*)&W[(size_t)(k + kk) * N + c0];
        w[0] = wv.x; w[1] = wv.y; w[2] = wv.z; w[3] = wv.w;
      }
      #pragma unroll
      for (int r = 0; r < 8; ++r) {
        const float xs = ((const float*)&xv[r])[kk];
        #pragma unroll
        for (int u = 0; u < CPT; ++u) acc[r][u] += xs * w[u];
      }
    }
  }
  #pragma unroll
  for (int r = 0; r < 8; ++r)
    #pragma unroll
    for (int u = 0; u < CPT; ++u)
      Y[(size_t)(row0 + r) * N + c0 + u] = acc[r][u];
}

// Merged pre-kernel. Branch is block-uniform.
__global__ __launch_bounds__(256) void pre_kernel(
    const float* __restrict__ q, const float* __restrict__ k,
    const float* __restrict__ Wq, const float* __restrict__ Wkv,
    const float* __restrict__ W1, const float* __restrict__ W2,
    float* __restrict__ qh_ws, float* __restrict__ kv_ws,
    unsigned short* __restrict__ W1f, unsigned short* __restrict__ W2f)
{
  const int bid = blockIdx.x;
  const int t = threadIdx.x;
  if (bid < 512)        proj_body<DH, 2>   (q, Wq,  qh_ws, bid, t);
  else if (bid < 1024)  proj_body<2*DH, 4> (k, Wkv, kv_ws, bid - 512, t);
  else if (bid < 1152)  swz_body<DH>       (W1, W1f, bid - 1024, t);
  else                  swz_body<2*DH>     (W2, W2f, bid - 1152, t);
}

// ---------------------------------------------------------------------------
// K3: fused MFMA pos-MLP + gather + attention + out-projection.
// Stage-1 A-frags now come straight from global pos (no LDS staging).
// ---------------------------------------------------------------------------
__global__ __launch_bounds__(256, 2) void fused_mfma(
    const float* __restrict__ pos, const int* __restrict__ lidx,
    const float* __restrict__ qh, const float* __restrict__ kv,
    const unsigned short* __restrict__ W1f, const float* __restrict__ b1,
    const unsigned short* __restrict__ W2f, const float* __restrict__ b2,
    const float* __restrict__ Wout, float* __restrict__ out)
{
  __shared__ unsigned short s_a[G_ * 16 * 64 * 8];   // 64 KB: hidden frags + epilogue overlay

  const int t    = threadIdx.x;
  const int lane = t & 63;
  const int w    = t >> 6;        // wave 0..3
  const int g    = lane >> 4;     // row-group within C layout
  const int c16  = lane & 15;     // col within 16-tile
  const int bi0  = blockIdx.x * G_;
  const int b    = bi0 >> 11;     // / I_

  // local_idx may be int64 (reference) or int32; detect (values < 2048 so
  // int64 high words are all zero).
  bool idx64;
  {
    int orv = 0;
    #pragma unroll
    for (int m = 0; m < 16; ++m) orv |= lidx[2 * m + 1];
    idx64 = (orv == 0);
  }
  // gather indices this lane needs: j = g*4 + r for each i (=m-tile)
  int idxr[G_][4];
  #pragma unroll
  for (int mt = 0; mt < G_; ++mt)
    #pragma unroll
    for (int r = 0; r < 4; ++r) {
      const int e = (bi0 + mt) * J_ + g * 4 + r;
      idxr[mt][r] = idx64 ? lidx[2 * e] : lidx[e];
    }

  const f32x4 zero4 = {0.f, 0.f, 0.f, 0.f};

  // ---- stage 1: hidden = relu(pos @ W1 + b1); wave w owns cols w*128.. ----
  // A-frag (mt, ks) for lane l: pos row bi0*16 + mt*16 + (l&15),
  // cols ks*32 + (l>>4)*8 .. +8  -> two contiguous float4 loads from global.
  f32x4 acc1[G_][8];
  #pragma unroll
  for (int mt = 0; mt < G_; ++mt)
    #pragma unroll
    for (int nt = 0; nt < 8; ++nt) acc1[mt][nt] = zero4;

  const float* pb = pos + ((size_t)bi0 * J_ + (lane & 15)) * DH + ((lane >> 4) << 3);

  float4 p0[G_], p1[G_];
  #pragma unroll
  for (int mt = 0; mt < G_; ++mt) {
    const float* s = pb + mt * 16 * DH;
    p0[mt] = *(const float4*)s;
    p1[mt] = *(const float4*)(s + 4);
  }
  #pragma unroll 2
  for (int ks = 0; ks < 16; ++ks) {
    bf16x8 a[G_];
    #pragma unroll
    for (int mt = 0; mt < G_; ++mt) a[mt] = cvt8(p0[mt], p1[mt]);
    // prefetch next ks (clamped: last iter harmlessly re-loads ks=15)
    const int ksn = (ks < 15) ? ks + 1 : 15;
    #pragma unroll
    for (int mt = 0; mt < G_; ++mt) {
      const float* s = pb + mt * 16 * DH + ksn * 32;
      p0[mt] = *(const float4*)s;
      p1[mt] = *(const float4*)(s + 4);
    }
    #pragma unroll
    for (int nt = 0; nt < 8; ++nt) {
      const int ntg = w * 8 + nt;
      const bf16x8 bf = *(const bf16x8*)&W1f[((size_t)(ntg * 16 + ks) * 64 + lane) * 8];
      #pragma unroll
      for (int mt = 0; mt < G_; ++mt)
        acc1[mt][nt] = __builtin_amdgcn_mfma_f32_16x16x32_bf16(a[mt], bf, acc1[mt][nt], 0, 0, 0);
    }
  }
  // no barrier needed: s_a untouched so far; scatter below writes disjoint bytes

  // ---- relu + b1, scatter into s_a as stage-2 A-frags ----
  #pragma unroll
  for (int nt = 0; nt < 8; ++nt) {
    const int col  = (w * 8 + nt) * 16 + c16;
    const float bb = b1[col];
    const int ks2  = col >> 5;
    const int lsel = ((col >> 3) & 3) * 16;
    const int bj   = col & 7;
    #pragma unroll
    for (int mt = 0; mt < G_; ++mt)
      #pragma unroll
      for (int r = 0; r < 4; ++r) {
        const float hv = fmaxf(acc1[mt][nt][r] + bb, 0.f);
        s_a[((mt * 16 + ks2) * 64 + (g * 4 + r) + lsel) * 8 + bj] = f2bf(hv);
      }
  }
  __syncthreads();

  // ---- stage 2 + attention: one head per pass; wave w -> heads 2w, 2w+1 ----
  float agg[2][G_][4];   // [pass][i][d-tile]
  #pragma unroll
  for (int p = 0; p < 2; ++p) {
    const int h = 2 * w + p;
    f32x4 acc2[G_][8];   // tt 0..3 = K-side (d = tt*16+c16), 4..7 = V-side
    #pragma unroll
    for (int mt = 0; mt < G_; ++mt)
      #pragma unroll
      for (int tt = 0; tt < 8; ++tt) acc2[mt][tt] = zero4;

    bf16x8 an[G_];
    #pragma unroll
    for (int mt = 0; mt < G_; ++mt)
      an[mt] = *(const bf16x8*)&s_a[((mt * 16 + 0) * 64 + lane) * 8];

    #pragma unroll 2
    for (int ks = 0; ks < 16; ++ks) {
      bf16x8 a[G_];
      #pragma unroll
      for (int mt = 0; mt < G_; ++mt) a[mt] = an[mt];
      const int ksn = (ks < 15) ? ks + 1 : 15;
      #pragma unroll
      for (int mt = 0; mt < G_; ++mt)
        an[mt] = *(const bf16x8*)&s_a[((mt * 16 + ksn) * 64 + lane) * 8];
      #pragma unroll
      for (int tt = 0; tt < 8; ++tt) {
        const int ntg = h * 8 + tt;   // pos_kv cols h*128 + tt*16 ..
        const bf16x8 bf = *(const bf16x8*)&W2f[((size_t)(ntg * 16 + ks) * 64 + lane) * 8];
        #pragma unroll
        for (int mt = 0; mt < G_; ++mt)
          acc2[mt][tt] = __builtin_amdgcn_mfma_f32_16x16x32_bf16(a[mt], bf, acc2[mt][tt], 0, 0, 0);
      }
    }

    // epilogue for head h (all f32). C layout: col = c16, row m = g*4 + reg.
    float b2k[4], b2v[4], qv[G_][4];
    #pragma unroll
    for (int tt = 0; tt < 4; ++tt) {
      b2k[tt] = b2[h * 128 + tt * 16 + c16];
      b2v[tt] = b2[h * 128 + 64 + tt * 16 + c16];
    }
    #pragma unroll
    for (int mt = 0; mt < G_; ++mt)
      #pragma unroll
      for (int tt = 0; tt < 4; ++tt)
        qv[mt][tt] = qh[(size_t)(bi0 + mt) * DH + h * 64 + tt * 16 + c16];

    #pragma unroll
    for (int mt = 0; mt < G_; ++mt) {
      float pj[4];
      #pragma unroll
      for (int r = 0; r < 4; ++r) {
        const float* kvrow = kv + ((size_t)b * NK_ + idxr[mt][r]) * (2 * DH);
        float s = 0.f;
        #pragma unroll
        for (int tt = 0; tt < 4; ++tt) {
          const int d = h * 64 + tt * 16 + c16;
          const float kg = acc2[mt][tt][r] + b2k[tt] + kvrow[d];
          s += qv[mt][tt] * kg;
          acc2[mt][4 + tt][r] += b2v[tt] + kvrow[DH + d];   // vg in place
        }
        s += __shfl_xor(s, 1);  s += __shfl_xor(s, 2);
        s += __shfl_xor(s, 4);  s += __shfl_xor(s, 8);      // full q.kg
        pj[r] = s * 0.125f;                                  // D_K^-0.5
      }
      // softmax over the 16 j (j = g*4 + r): cross-group via xor 16/32
      float mx = fmaxf(fmaxf(pj[0], pj[1]), fmaxf(pj[2], pj[3]));
      mx = fmaxf(mx, __shfl_xor(mx, 16));
      mx = fmaxf(mx, __shfl_xor(mx, 32));
      float sum = 0.f;
      #pragma unroll
      for (int r = 0; r < 4; ++r) { pj[r] = __expf(pj[r] - mx); sum += pj[r]; }
      sum += __shfl_xor(sum, 16);
      sum += __shfl_xor(sum, 32);
      const float inv = 1.f / sum;
      #pragma unroll
      for (int r = 0; r < 4; ++r) pj[r] *= inv;
      // V aggregation; xor 16/32 sums over all j groups
      #pragma unroll
      for (int tt = 0; tt < 4; ++tt) {
        float a_ = pj[0] * acc2[mt][4 + tt][0] + pj[1] * acc2[mt][4 + tt][1]
                 + pj[2] * acc2[mt][4 + tt][2] + pj[3] * acc2[mt][4 + tt][3];
        a_ += __shfl_xor(a_, 16);
        a_ += __shfl_xor(a_, 32);
        agg[p][mt][tt] = a_;
      }
    }
  }
  __syncthreads();   // all waves done reading s_a (hidden frags)

  // ---- write agg into s_a overlay: s_agg[i][512] f32 (8 KB) ----
  float* s_agg = (float*)s_a;
  if (g == 0) {
    #pragma unroll
    for (int p = 0; p < 2; ++p) {
      const int h = 2 * w + p;
      #pragma unroll
      for (int mt = 0; mt < G_; ++mt)
        #pragma unroll
        for (int tt = 0; tt < 4; ++tt)
          s_agg[mt * DH + h * 64 + tt * 16 + c16] = agg[p][mt][tt];
    }
  }
  __syncthreads();

  // ---- out = agg @ Wout; wave w sums k-range [w*128, w*128+128) ----
  float* s_part = (float*)s_a + G_ * DH;   // bytes [8KB, 24KB)
  f32x4 oacc[G_];
  #pragma unroll
  for (int i = 0; i < G_; ++i) oacc[i] = zero4;
  for (int c4 = 0; c4 < 32; ++c4) {
    const int c = w * 128 + c4 * 4;
    f32x4 ag[G_];
    #pragma unroll
    for (int i = 0; i < G_; ++i) ag[i] = *(const f32x4*)&s_agg[i * DH + c];
    #pragma unroll
    for (int cc = 0; cc < 4; ++cc) {
      const f32x4 wv = *(const f32x4*)&Wout[(size_t)(c + cc) * DM + lane * 4];
      #pragma unroll
      for (int i = 0; i < G_; ++i) oacc[i] += wv * ag[i][cc];
    }
  }
  #pragma unroll
  for (int i = 0; i < G_; ++i)
    *(f32x4*)&s_part[(w * G_ + i) * DM + lane * 4] = oacc[i];
  __syncthreads();

  #pragma unroll
  for (int i = 0; i < G_; ++i) {
    const float o = s_part[(0 * G_ + i) * DM + t] + s_part[(1 * G_ + i) * DM + t]
                  + s_part[(2 * G_ + i) * DM + t] + s_part[(3 * G_ + i) * DM + t];
    out[(size_t)(bi0 + i) * DM + t] = o;
  }
}

// ---------------------------------------------------------------------------
extern "C" void kernel_launch(void* const* d_in, const int* in_sizes, int n_in,
                              void* d_out, int out_size, void* d_ws, size_t ws_size,
                              hipStream_t stream)
{
  const float* q    = (const float*)d_in[0];
  const float* k    = (const float*)d_in[1];
  const float* pos  = (const float*)d_in[2];
  const int*   lidx = (const int*)d_in[3];
  const float* Wq   = (const float*)d_in[4];
  const float* Wkv  = (const float*)d_in[5];
  const float* W1   = (const float*)d_in[6];
  const float* b1   = (const float*)d_in[7];
  const float* W2   = (const float*)d_in[8];
  const float* b2   = (const float*)d_in[9];
  const float* Wout = (const float*)d_in[10];
  float* out = (float*)d_out;

  // ws: qh 8MB | kv 16MB | W1f 512KB | W2f 1MB
  float* qh_ws = (float*)d_ws;
  float* kv_ws = qh_ws + (size_t)(B_ * I_) * DH;
  unsigned short* W1f = (unsigned short*)(kv_ws + (size_t)(B_ * NK_) * (2 * DH));
  unsigned short* W2f = W1f + (size_t)DH * DH;

  pre_kernel<<<1408, 256, 0, stream>>>(q, k, Wq, Wkv, W1, W2,
                                       qh_ws, kv_ws, W1f, W2f);
  fused_mfma<<<(B_ * I_) / G_, 256, 0, stream>>>(pos, lidx, qh_ws, kv_ws,
                                                 W1f, b1, W2f, b2, Wout, out);
}

// Round 4
// 431.591 us; speedup vs baseline: 1.1362x; 1.1362x over previous
//
#include <hip/hip_runtime.h>
#include <hip/hip_bf16.h>
#include <cstddef>

// MultiHeadedCrossAttention, Round 8 (= R7 resubmit; R7 hit an infra
// failure, never ran).
// B=2, I=2048, J=16, NK=2048, D_MODEL=256, D_HIDDEN=512, H=8, D_K=64.
//
// Theory: both MFMA stages serialize as per-nt {load B-frag -> wait ->
// 4xMFMA}: 8 L2-latency exposures per ks-step, only 2 waves/SIMD to cover
// them (MfmaUtil 15% == MFMA-floor/dur). Changes vs verified R4 lineage:
//  * Batch all 8 B-frag loads per ks into bfr[8] BEFORE the 32-MFMA
//    cluster: one latency exposure per ks instead of eight.
//  * Pay for +28 VGPR by killing the cross-pass agg[2][4][4] liveness:
//    each pass writes its attention output straight to a separate 8KB
//    s_agg2 LDS buffer (LDS 72KB total, still 2 blocks/CU).
//  * pre_kernel proj_body: hoist the 4 W-row loads out of the kk loop
//    (batch 4 loads -> one wait -> 32*CPT FMAs).

#define B_  2
#define I_  2048
#define J_  16
#define NK_ 2048
#define DM  256
#define DH  512
#define H_  8
#define DK  64
#define G_  4    // i's per fused block

typedef __attribute__((ext_vector_type(8))) __bf16 bf16x8;
typedef __attribute__((ext_vector_type(4))) float f32x4;
typedef __attribute__((ext_vector_type(8))) unsigned short ushort8;

__device__ inline unsigned short f2bf(float f) {   // RNE float->bf16
  unsigned int u = __builtin_bit_cast(unsigned int, f);
  u += 0x7FFFu + ((u >> 16) & 1u);
  return (unsigned short)(u >> 16);
}

// ---------------------------------------------------------------------------
// Pre-kernel bodies
// ---------------------------------------------------------------------------

// Weight pre-swizzle: W (512 x N f32 row-major) -> bf16 B-frags. (R2-verbatim)
// Frag (nt, ks): lane l holds B[k = ks*32 + (l>>4)*8 + j][n = nt*16 + (l&15)],
// j=0..7, 16B-contiguous at Wf[((nt*16+ks)*64 + l)*8].
template<int N>
__device__ void swz_body(const float* __restrict__ W,
                         unsigned short* __restrict__ Wf, int bid, int t)
{
  const int u  = bid * 256 + t;
  const int l  = u & 63;
  const int fi = u >> 6;
  const int ks = fi & 15;
  const int nt = fi >> 4;
  const int n  = nt * 16 + (l & 15);
  const int k0 = ks * 32 + (l >> 4) * 8;
  unsigned short tmp[8];
  #pragma unroll
  for (int j = 0; j < 8; ++j) tmp[j] = f2bf(W[(size_t)(k0 + j) * N + n]);
  *(ushort8*)&Wf[(size_t)u * 8] = *(const ushort8*)tmp;
}

// Y = X @ W, X: (rows, 256) f32, LDS-staged X. W loads batched per k-group.
template<int N, int CPT>
__device__ void proj_body(const float* __restrict__ X,
                          const float* __restrict__ W,
                          float* __restrict__ Y, float* Xs, int bid, int t)
{
  const int row0 = bid * 8;
  {
    const float4* x4 = (const float4*)(X + (size_t)row0 * DM);
    float4* s4 = (float4*)Xs;
    s4[t] = x4[t]; s4[t + 256] = x4[t + 256];
  }
  __syncthreads();

  float acc[8][CPT];
  #pragma unroll
  for (int r = 0; r < 8; ++r)
    #pragma unroll
    for (int u = 0; u < CPT; ++u) acc[r][u] = 0.f;

  const int c0 = t * CPT;
  for (int k = 0; k < DM; k += 4) {
    float4 xv[8];
    #pragma unroll
    for (int r = 0; r < 8; ++r) xv[r] = *(const float4*)&Xs[r * DM + k];
    // batched W loads: all 4 kk rows in flight before the FMA cluster
    float w4[4][CPT];
    #pragma unroll
    for (int kk = 0; kk < 4; ++kk) {
      if constexpr (CPT == 2) {
        const float2 wv = *(const float2*)&W[(size_t)(k + kk) * N + c0];
        w4[kk][0] = wv.x; w4[kk][1] = wv.y;
      } else {
        const float4 wv = *(const float4*)&W[(size_t)(k + kk) * N + c0];
        w4[kk][0] = wv.x; w4[kk][1] = wv.y; w4[kk][2] = wv.z; w4[kk][3] = wv.w;
      }
    }
    #pragma unroll
    for (int kk = 0; kk < 4; ++kk) {
      #pragma unroll
      for (int r = 0; r < 8; ++r) {
        const float xs = ((const float*)&xv[r])[kk];
        #pragma unroll
        for (int u = 0; u < CPT; ++u) acc[r][u] += xs * w4[kk][u];
      }
    }
  }
  #pragma unroll
  for (int r = 0; r < 8; ++r)
    #pragma unroll
    for (int u = 0; u < CPT; ++u)
      Y[(size_t)(row0 + r) * N + c0 + u] = acc[r][u];
}

// Merged pre-kernel. Branch is block-uniform.
__global__ __launch_bounds__(256) void pre_kernel(
    const float* __restrict__ q, const float* __restrict__ k,
    const float* __restrict__ Wq, const float* __restrict__ Wkv,
    const float* __restrict__ W1, const float* __restrict__ W2,
    float* __restrict__ qh_ws, float* __restrict__ kv_ws,
    unsigned short* __restrict__ W1f, unsigned short* __restrict__ W2f)
{
  __shared__ float Xs[8 * DM];
  const int bid = blockIdx.x;
  const int t = threadIdx.x;
  if (bid < 512)        proj_body<DH, 2>   (q, Wq,  qh_ws, Xs, bid, t);
  else if (bid < 1024)  proj_body<2*DH, 4> (k, Wkv, kv_ws, Xs, bid - 512, t);
  else if (bid < 1152)  swz_body<DH>       (W1, W1f, bid - 1024, t);
  else                  swz_body<2*DH>     (W2, W2f, bid - 1152, t);
}

// ---------------------------------------------------------------------------
// K3: fused MFMA pos-MLP + gather + attention + out-projection.
// G_=4, pos staged in LDS (verified R2/R4 lineage), batched B-frag loads.
// ---------------------------------------------------------------------------
__global__ __launch_bounds__(256, 2) void fused_mfma(
    const float* __restrict__ pos, const int* __restrict__ lidx,
    const float* __restrict__ qh, const float* __restrict__ kv,
    const unsigned short* __restrict__ W1f, const float* __restrict__ b1,
    const unsigned short* __restrict__ W2f, const float* __restrict__ b2,
    const float* __restrict__ Wout, float* __restrict__ out)
{
  __shared__ unsigned short s_a[G_ * 16 * 64 * 8];   // 64 KB: pos frags -> hidden frags -> s_part
  __shared__ float s_agg2[G_ * DH];                  // 8 KB: attention output

  const int t    = threadIdx.x;
  const int lane = t & 63;
  const int w    = t >> 6;        // wave 0..3
  const int g    = lane >> 4;     // row-group within C layout
  const int c16  = lane & 15;     // col within 16-tile
  const int bi0  = blockIdx.x * G_;
  const int b    = bi0 >> 11;     // / I_

  // local_idx may be int64 (reference) or int32; detect (values < 2048 so
  // int64 high words are all zero).
  bool idx64;
  {
    int orv = 0;
    #pragma unroll
    for (int m = 0; m < 16; ++m) orv |= lidx[2 * m + 1];
    idx64 = (orv == 0);
  }
  // gather indices this lane needs: j = g*4 + r for each i (=m-tile)
  int idxr[G_][4];
  #pragma unroll
  for (int mt = 0; mt < G_; ++mt)
    #pragma unroll
    for (int r = 0; r < 4; ++r) {
      const int e = (bi0 + mt) * J_ + g * 4 + r;
      idxr[mt][r] = idx64 ? lidx[2 * e] : lidx[e];
    }

  // ---- stage pos (64 rows x 512 cols) -> s_a in A-frag order (bf16) ----
  #pragma unroll
  for (int it = 0; it < 16; ++it) {
    const int u  = t + it * 256;
    const int fi = u >> 6, ld = u & 63;
    const int mt = fi >> 4, ks = fi & 15;
    const int row = mt * 16 + (ld & 15);
    const int col = ks * 32 + (ld >> 4) * 8;
    const float* src = pos + (size_t)(bi0 * J_ + row) * DH + col;
    const float4 v0 = *(const float4*)src;
    const float4 v1 = *(const float4*)(src + 4);
    unsigned short tmp[8];
    tmp[0] = f2bf(v0.x); tmp[1] = f2bf(v0.y); tmp[2] = f2bf(v0.z); tmp[3] = f2bf(v0.w);
    tmp[4] = f2bf(v1.x); tmp[5] = f2bf(v1.y); tmp[6] = f2bf(v1.z); tmp[7] = f2bf(v1.w);
    *(ushort8*)&s_a[(size_t)u * 8] = *(const ushort8*)tmp;
  }
  __syncthreads();

  const f32x4 zero4 = {0.f, 0.f, 0.f, 0.f};

  // ---- stage 1: hidden = relu(pos @ W1 + b1); wave w owns cols w*128.. ----
  f32x4 acc1[G_][8];
  #pragma unroll
  for (int mt = 0; mt < G_; ++mt)
    #pragma unroll
    for (int nt = 0; nt < 8; ++nt) acc1[mt][nt] = zero4;

  for (int ks = 0; ks < 16; ++ks) {
    bf16x8 a[G_];
    #pragma unroll
    for (int mt = 0; mt < G_; ++mt)
      a[mt] = *(const bf16x8*)&s_a[((mt * 16 + ks) * 64 + lane) * 8];
    // batched B-frag loads: all 8 in flight before the MFMA cluster
    bf16x8 bfr[8];
    #pragma unroll
    for (int nt = 0; nt < 8; ++nt)
      bfr[nt] = *(const bf16x8*)&W1f[((size_t)((w * 8 + nt) * 16 + ks) * 64 + lane) * 8];
    #pragma unroll
    for (int nt = 0; nt < 8; ++nt)
      #pragma unroll
      for (int mt = 0; mt < G_; ++mt)
        acc1[mt][nt] = __builtin_amdgcn_mfma_f32_16x16x32_bf16(a[mt], bfr[nt], acc1[mt][nt], 0, 0, 0);
  }
  __syncthreads();   // everyone done reading pos frags

  // ---- relu + b1, scatter into s_a as stage-2 A-frags ----
  #pragma unroll
  for (int nt = 0; nt < 8; ++nt) {
    const int col  = (w * 8 + nt) * 16 + c16;
    const float bb = b1[col];
    const int ks2  = col >> 5;
    const int lsel = ((col >> 3) & 3) * 16;
    const int bj   = col & 7;
    #pragma unroll
    for (int mt = 0; mt < G_; ++mt)
      #pragma unroll
      for (int r = 0; r < 4; ++r) {
        const float hv = fmaxf(acc1[mt][nt][r] + bb, 0.f);
        s_a[((mt * 16 + ks2) * 64 + (g * 4 + r) + lsel) * 8 + bj] = f2bf(hv);
      }
  }
  __syncthreads();

  // ---- stage 2 + attention: one head per pass; wave w -> heads 2w, 2w+1 ----
  #pragma unroll
  for (int p = 0; p < 2; ++p) {
    const int h = 2 * w + p;
    f32x4 acc2[G_][8];   // tt 0..3 = K-side (d = tt*16+c16), 4..7 = V-side
    #pragma unroll
    for (int mt = 0; mt < G_; ++mt)
      #pragma unroll
      for (int tt = 0; tt < 8; ++tt) acc2[mt][tt] = zero4;

    for (int ks = 0; ks < 16; ++ks) {
      bf16x8 a[G_];
      #pragma unroll
      for (int mt = 0; mt < G_; ++mt)
        a[mt] = *(const bf16x8*)&s_a[((mt * 16 + ks) * 64 + lane) * 8];
      // batched B-frag loads
      bf16x8 bfr[8];
      #pragma unroll
      for (int tt = 0; tt < 8; ++tt)
        bfr[tt] = *(const bf16x8*)&W2f[((size_t)((h * 8 + tt) * 16 + ks) * 64 + lane) * 8];
      #pragma unroll
      for (int tt = 0; tt < 8; ++tt)
        #pragma unroll
        for (int mt = 0; mt < G_; ++mt)
          acc2[mt][tt] = __builtin_amdgcn_mfma_f32_16x16x32_bf16(a[mt], bfr[tt], acc2[mt][tt], 0, 0, 0);
    }

    // epilogue for head h (all f32). C layout: col = c16, row m = g*4 + reg.
    float b2k[4], b2v[4], qv[G_][4];
    #pragma unroll
    for (int tt = 0; tt < 4; ++tt) {
      b2k[tt] = b2[h * 128 + tt * 16 + c16];
      b2v[tt] = b2[h * 128 + 64 + tt * 16 + c16];
    }
    #pragma unroll
    for (int mt = 0; mt < G_; ++mt)
      #pragma unroll
      for (int tt = 0; tt < 4; ++tt)
        qv[mt][tt] = qh[(size_t)(bi0 + mt) * DH + h * 64 + tt * 16 + c16];

    #pragma unroll
    for (int mt = 0; mt < G_; ++mt) {
      float pj[4];
      #pragma unroll
      for (int r = 0; r < 4; ++r) {
        const float* kvrow = kv + ((size_t)b * NK_ + idxr[mt][r]) * (2 * DH);
        float s = 0.f;
        #pragma unroll
        for (int tt = 0; tt < 4; ++tt) {
          const int d = h * 64 + tt * 16 + c16;
          const float kg = acc2[mt][tt][r] + b2k[tt] + kvrow[d];
          s += qv[mt][tt] * kg;
          acc2[mt][4 + tt][r] += b2v[tt] + kvrow[DH + d];   // vg in place
        }
        s += __shfl_xor(s, 1);  s += __shfl_xor(s, 2);
        s += __shfl_xor(s, 4);  s += __shfl_xor(s, 8);      // full q.kg
        pj[r] = s * 0.125f;                                  // D_K^-0.5
      }
      // softmax over the 16 j (j = g*4 + r): cross-group via xor 16/32
      float mx = fmaxf(fmaxf(pj[0], pj[1]), fmaxf(pj[2], pj[3]));
      mx = fmaxf(mx, __shfl_xor(mx, 16));
      mx = fmaxf(mx, __shfl_xor(mx, 32));
      float sum = 0.f;
      #pragma unroll
      for (int r = 0; r < 4; ++r) { pj[r] = __expf(pj[r] - mx); sum += pj[r]; }
      sum += __shfl_xor(sum, 16);
      sum += __shfl_xor(sum, 32);
      const float inv = 1.f / sum;
      #pragma unroll
      for (int r = 0; r < 4; ++r) pj[r] *= inv;
      // V aggregation; xor 16/32 sums over all j groups; write straight to
      // s_agg2 (separate buffer -- no conflict with s_a readers in other waves)
      #pragma unroll
      for (int tt = 0; tt < 4; ++tt) {
        float a_ = pj[0] * acc2[mt][4 + tt][0] + pj[1] * acc2[mt][4 + tt][1]
                 + pj[2] * acc2[mt][4 + tt][2] + pj[3] * acc2[mt][4 + tt][3];
        a_ += __shfl_xor(a_, 16);
        a_ += __shfl_xor(a_, 32);
        if (g == 0)
          s_agg2[mt * DH + h * 64 + tt * 16 + c16] = a_;
      }
    }
  }
  __syncthreads();   // s_agg2 complete; all waves done reading s_a

  // ---- out = agg @ Wout; wave w sums k-range [w*128, w*128+128) ----
  float* s_part = (float*)s_a;   // 16 KB overlay, pos/hidden frags dead now
  f32x4 oacc[G_];
  #pragma unroll
  for (int i = 0; i < G_; ++i) oacc[i] = zero4;
  for (int c4 = 0; c4 < 32; ++c4) {
    const int c = w * 128 + c4 * 4;
    f32x4 ag[G_];
    #pragma unroll
    for (int i = 0; i < G_; ++i) ag[i] = *(const f32x4*)&s_agg2[i * DH + c];
    #pragma unroll
    for (int cc = 0; cc < 4; ++cc) {
      const f32x4 wv = *(const f32x4*)&Wout[(size_t)(c + cc) * DM + lane * 4];
      #pragma unroll
      for (int i = 0; i < G_; ++i) oacc[i] += wv * ag[i][cc];
    }
  }
  #pragma unroll
  for (int i = 0; i < G_; ++i)
    *(f32x4*)&s_part[(w * G_ + i) * DM + lane * 4] = oacc[i];
  __syncthreads();

  #pragma unroll
  for (int i = 0; i < G_; ++i) {
    const float o = s_part[(0 * G_ + i) * DM + t] + s_part[(1 * G_ + i) * DM + t]
                  + s_part[(2 * G_ + i) * DM + t] + s_part[(3 * G_ + i) * DM + t];
    out[(size_t)(bi0 + i) * DM + t] = o;
  }
}

// ---------------------------------------------------------------------------
extern "C" void kernel_launch(void* const* d_in, const int* in_sizes, int n_in,
                              void* d_out, int out_size, void* d_ws, size_t ws_size,
                              hipStream_t stream)
{
  const float* q    = (const float*)d_in[0];
  const float* k    = (const float*)d_in[1];
  const float* pos  = (const float*)d_in[2];
  const int*   lidx = (const int*)d_in[3];
  const float* Wq   = (const float*)d_in[4];
  const float* Wkv  = (const float*)d_in[5];
  const float* W1   = (const float*)d_in[6];
  const float* b1   = (const float*)d_in[7];
  const float* W2   = (const float*)d_in[8];
  const float* b2   = (const float*)d_in[9];
  const float* Wout = (const float*)d_in[10];
  float* out = (float*)d_out;

  // ws: qh 8MB | kv 16MB | W1f 512KB | W2f 1MB
  float* qh_ws = (float*)d_ws;
  float* kv_ws = qh_ws + (size_t)(B_ * I_) * DH;
  unsigned short* W1f = (unsigned short*)(kv_ws + (size_t)(B_ * NK_) * (2 * DH));
  unsigned short* W2f = W1f + (size_t)DH * DH;

  pre_kernel<<<1408, 256, 0, stream>>>(q, k, Wq, Wkv, W1, W2,
                                       qh_ws, kv_ws, W1f, W2f);
  fused_mfma<<<(B_ * I_) / G_, 256, 0, stream>>>(pos, lidx, qh_ws, kv_ws,
                                                 W1f, b1, W2f, b2, Wout, out);
}

// Round 6
// 393.623 us; speedup vs baseline: 1.2458x; 1.0965x over previous
//
#include <hip/hip_runtime.h>
#include <hip/hip_bf16.h>
#include <cstddef>

// MultiHeadedCrossAttention, Round 10.
// B=2, I=2048, J=16, NK=2048, D_MODEL=256, D_HIDDEN=512, H=8, D_K=64.
//
// R9 post-mortem: W1f/W2f B-frag prefetch-rotation is the recurring
// corruption carrier (R3+R9, both ~2e-2) -> BANNED. fused_mfma stays
// R8-VERBATIM (verified 212us, MfmaUtil 20%).
// R10 attacks pre (~175-220us for ~20us of work): replace the scalar-FMA
// f32 projections (64 serial L2-latency exposures/block on the vector
// pipe) with MFMA bf16 projections reusing ONLY verified machinery:
//  * swz_body generalized to K=256 (template<N,KS>); layout identical to
//    the verified K=512 case for W1/W2.
//  * A-frags from global f32 via cvt8 (R5-verified address math).
//  * R8's batched-load loop shape: per ks, 8 A-loads + 8 B-loads batched,
//    then 32 MFMAs. No prefetch rotation anywhere.
//  * C written via the verified layout: col=c16, row=g*4+r.
// Launches: swz(576 blk) -> proj_mfma(128 blk) -> fused(1024 blk).
// Numerics: qh/kv become bf16-product/f32-accum; expected absmax ~2-3e-3
// (threshold 5.5e-3).

#define B_  2
#define I_  2048
#define J_  16
#define NK_ 2048
#define DM  256
#define DH  512
#define H_  8
#define DK  64
#define G_  4    // i's per fused block

typedef __attribute__((ext_vector_type(8))) __bf16 bf16x8;
typedef __attribute__((ext_vector_type(4))) float f32x4;
typedef __attribute__((ext_vector_type(8))) unsigned short ushort8;

__device__ inline unsigned short f2bf(float f) {   // RNE float->bf16
  unsigned int u = __builtin_bit_cast(unsigned int, f);
  u += 0x7FFFu + ((u >> 16) & 1u);
  return (unsigned short)(u >> 16);
}

// 8x f32 -> bf16x8 via native converts (v_cvt_pk_bf16_f32, RNE == f2bf).
__device__ inline bf16x8 cvt8(float4 a, float4 b) {
  bf16x8 r;
  r[0] = (__bf16)a.x; r[1] = (__bf16)a.y; r[2] = (__bf16)a.z; r[3] = (__bf16)a.w;
  r[4] = (__bf16)b.x; r[5] = (__bf16)b.y; r[6] = (__bf16)b.z; r[7] = (__bf16)b.w;
  return r;
}

// ---------------------------------------------------------------------------
// Weight pre-swizzle: W (K x N f32 row-major) -> bf16 B-frags.
// Frag (nt, ks): lane l holds B[k = ks*32 + (l>>4)*8 + j][n = nt*16 + (l&15)],
// j=0..7, 16B-contiguous at Wf[((nt*KS + ks)*64 + l)*8].  KS = K/32.
// For KS=16 this is bit-identical to the verified W1/W2 layout.
// ---------------------------------------------------------------------------
template<int N, int KS>
__device__ void swz_body(const float* __restrict__ W,
                         unsigned short* __restrict__ Wf, int bid, int t)
{
  const int u  = bid * 256 + t;
  const int l  = u & 63;
  const int fi = u >> 6;
  const int ks = fi % KS;
  const int nt = fi / KS;
  const int n  = nt * 16 + (l & 15);
  const int k0 = ks * 32 + (l >> 4) * 8;
  unsigned short tmp[8];
  #pragma unroll
  for (int j = 0; j < 8; ++j) tmp[j] = f2bf(W[(size_t)(k0 + j) * N + n]);
  *(ushort8*)&Wf[(size_t)u * 8] = *(const ushort8*)tmp;
}

// Swizzle all four weights. Block-uniform branch.
// Wq: N=512,KS=8 -> 64 blk | Wkv: N=1024,KS=8 -> 128 | W1: 512,16 -> 128 |
// W2: 1024,16 -> 256. Total 576.
__global__ __launch_bounds__(256) void swz_kernel(
    const float* __restrict__ Wq, const float* __restrict__ Wkv,
    const float* __restrict__ W1, const float* __restrict__ W2,
    unsigned short* __restrict__ Wqf, unsigned short* __restrict__ Wkvf,
    unsigned short* __restrict__ W1f, unsigned short* __restrict__ W2f)
{
  const int bid = blockIdx.x;
  const int t = threadIdx.x;
  if (bid < 64)        swz_body<DH, 8>    (Wq,  Wqf,  bid,       t);
  else if (bid < 192)  swz_body<2*DH, 8>  (Wkv, Wkvf, bid - 64,  t);
  else if (bid < 320)  swz_body<DH, 16>   (W1,  W1f,  bid - 192, t);
  else                 swz_body<2*DH, 16> (W2,  W2f,  bid - 320, t);
}

// ---------------------------------------------------------------------------
// MFMA projections: qh = q @ Wq (bid 0..63), kv = k @ Wkv (bid 64..127).
// Block = 64 rows x full N. Wave w owns cols w*128.. per half-pass.
// R8 loop shape: batched A-loads + batched B-loads -> 32 MFMAs. No LDS.
// ---------------------------------------------------------------------------
__global__ __launch_bounds__(256) void proj_mfma(
    const float* __restrict__ q, const float* __restrict__ k,
    const unsigned short* __restrict__ Wqf,
    const unsigned short* __restrict__ Wkvf,
    float* __restrict__ qh_ws, float* __restrict__ kv_ws)
{
  const int t    = threadIdx.x;
  const int lane = t & 63;
  const int w    = t >> 6;
  const int g    = lane >> 4;
  const int c16  = lane & 15;

  const bool is_kv = blockIdx.x >= 64;
  const int  bid   = is_kv ? (int)blockIdx.x - 64 : (int)blockIdx.x;
  const int  row0  = bid * 64;
  const float* X = is_kv ? k : q;
  const unsigned short* Wf = is_kv ? Wkvf : Wqf;
  const int  N     = is_kv ? 2 * DH : DH;
  float*     Y     = is_kv ? kv_ws : qh_ws;
  const int  passes = is_kv ? 2 : 1;

  const f32x4 zero4 = {0.f, 0.f, 0.f, 0.f};
  // A-frag base (R5-verified math): row = row0 + mt*16 + (lane&15),
  // col = ks*32 + (lane>>4)*8 .. +8
  const float* pa = X + (size_t)(row0 + (lane & 15)) * DM + ((lane >> 4) << 3);

  for (int hp = 0; hp < passes; ++hp) {
    f32x4 acc[G_][8];
    #pragma unroll
    for (int mt = 0; mt < G_; ++mt)
      #pragma unroll
      for (int nt = 0; nt < 8; ++nt) acc[mt][nt] = zero4;

    for (int ks = 0; ks < 8; ++ks) {          // K = 256 -> 8 steps
      bf16x8 a[G_];
      #pragma unroll
      for (int mt = 0; mt < G_; ++mt) {
        const float* s = pa + (size_t)mt * 16 * DM + ks * 32;
        a[mt] = cvt8(*(const float4*)s, *(const float4*)(s + 4));
      }
      bf16x8 bfr[8];
      #pragma unroll
      for (int nt = 0; nt < 8; ++nt) {
        const int ntg = hp * 32 + w * 8 + nt;
        bfr[nt] = *(const bf16x8*)&Wf[((size_t)(ntg * 8 + ks) * 64 + lane) * 8];
      }
      #pragma unroll
      for (int nt = 0; nt < 8; ++nt)
        #pragma unroll
        for (int mt = 0; mt < G_; ++mt)
          acc[mt][nt] = __builtin_amdgcn_mfma_f32_16x16x32_bf16(a[mt], bfr[nt], acc[mt][nt], 0, 0, 0);
    }

    // C write (verified layout: col = c16, row = g*4 + r)
    #pragma unroll
    for (int nt = 0; nt < 8; ++nt) {
      const int col = hp * 512 + (w * 8 + nt) * 16 + c16;
      #pragma unroll
      for (int mt = 0; mt < G_; ++mt)
        #pragma unroll
        for (int r = 0; r < 4; ++r)
          Y[(size_t)(row0 + mt * 16 + g * 4 + r) * N + col] = acc[mt][nt][r];
    }
  }
}

// ---------------------------------------------------------------------------
// K3: fused MFMA pos-MLP + gather + attention + out-projection.
// R8-VERBATIM (verified 212us, absmax 9.8e-4).
// ---------------------------------------------------------------------------
__global__ __launch_bounds__(256, 2) void fused_mfma(
    const float* __restrict__ pos, const int* __restrict__ lidx,
    const float* __restrict__ qh, const float* __restrict__ kv,
    const unsigned short* __restrict__ W1f, const float* __restrict__ b1,
    const unsigned short* __restrict__ W2f, const float* __restrict__ b2,
    const float* __restrict__ Wout, float* __restrict__ out)
{
  __shared__ unsigned short s_a[G_ * 16 * 64 * 8];   // 64 KB: pos frags -> hidden frags -> s_part
  __shared__ float s_agg2[G_ * DH];                  // 8 KB: attention output

  const int t    = threadIdx.x;
  const int lane = t & 63;
  const int w    = t >> 6;        // wave 0..3
  const int g    = lane >> 4;     // row-group within C layout
  const int c16  = lane & 15;     // col within 16-tile
  const int bi0  = blockIdx.x * G_;
  const int b    = bi0 >> 11;     // / I_

  // local_idx may be int64 (reference) or int32; detect (values < 2048 so
  // int64 high words are all zero).
  bool idx64;
  {
    int orv = 0;
    #pragma unroll
    for (int m = 0; m < 16; ++m) orv |= lidx[2 * m + 1];
    idx64 = (orv == 0);
  }
  // gather indices this lane needs: j = g*4 + r for each i (=m-tile)
  int idxr[G_][4];
  #pragma unroll
  for (int mt = 0; mt < G_; ++mt)
    #pragma unroll
    for (int r = 0; r < 4; ++r) {
      const int e = (bi0 + mt) * J_ + g * 4 + r;
      idxr[mt][r] = idx64 ? lidx[2 * e] : lidx[e];
    }

  // ---- stage pos (64 rows x 512 cols) -> s_a in A-frag order (bf16) ----
  #pragma unroll
  for (int it = 0; it < 16; ++it) {
    const int u  = t + it * 256;
    const int fi = u >> 6, ld = u & 63;
    const int mt = fi >> 4, ks = fi & 15;
    const int row = mt * 16 + (ld & 15);
    const int col = ks * 32 + (ld >> 4) * 8;
    const float* src = pos + (size_t)(bi0 * J_ + row) * DH + col;
    const float4 v0 = *(const float4*)src;
    const float4 v1 = *(const float4*)(src + 4);
    unsigned short tmp[8];
    tmp[0] = f2bf(v0.x); tmp[1] = f2bf(v0.y); tmp[2] = f2bf(v0.z); tmp[3] = f2bf(v0.w);
    tmp[4] = f2bf(v1.x); tmp[5] = f2bf(v1.y); tmp[6] = f2bf(v1.z); tmp[7] = f2bf(v1.w);
    *(ushort8*)&s_a[(size_t)u * 8] = *(const ushort8*)tmp;
  }
  __syncthreads();

  const f32x4 zero4 = {0.f, 0.f, 0.f, 0.f};

  // ---- stage 1: hidden = relu(pos @ W1 + b1); wave w owns cols w*128.. ----
  f32x4 acc1[G_][8];
  #pragma unroll
  for (int mt = 0; mt < G_; ++mt)
    #pragma unroll
    for (int nt = 0; nt < 8; ++nt) acc1[mt][nt] = zero4;

  for (int ks = 0; ks < 16; ++ks) {
    bf16x8 a[G_];
    #pragma unroll
    for (int mt = 0; mt < G_; ++mt)
      a[mt] = *(const bf16x8*)&s_a[((mt * 16 + ks) * 64 + lane) * 8];
    // batched B-frag loads: all 8 in flight before the MFMA cluster
    bf16x8 bfr[8];
    #pragma unroll
    for (int nt = 0; nt < 8; ++nt)
      bfr[nt] = *(const bf16x8*)&W1f[((size_t)((w * 8 + nt) * 16 + ks) * 64 + lane) * 8];
    #pragma unroll
    for (int nt = 0; nt < 8; ++nt)
      #pragma unroll
      for (int mt = 0; mt < G_; ++mt)
        acc1[mt][nt] = __builtin_amdgcn_mfma_f32_16x16x32_bf16(a[mt], bfr[nt], acc1[mt][nt], 0, 0, 0);
  }
  __syncthreads();   // everyone done reading pos frags

  // ---- relu + b1, scatter into s_a as stage-2 A-frags ----
  #pragma unroll
  for (int nt = 0; nt < 8; ++nt) {
    const int col  = (w * 8 + nt) * 16 + c16;
    const float bb = b1[col];
    const int ks2  = col >> 5;
    const int lsel = ((col >> 3) & 3) * 16;
    const int bj   = col & 7;
    #pragma unroll
    for (int mt = 0; mt < G_; ++mt)
      #pragma unroll
      for (int r = 0; r < 4; ++r) {
        const float hv = fmaxf(acc1[mt][nt][r] + bb, 0.f);
        s_a[((mt * 16 + ks2) * 64 + (g * 4 + r) + lsel) * 8 + bj] = f2bf(hv);
      }
  }
  __syncthreads();

  // ---- stage 2 + attention: one head per pass; wave w -> heads 2w, 2w+1 ----
  #pragma unroll
  for (int p = 0; p < 2; ++p) {
    const int h = 2 * w + p;
    f32x4 acc2[G_][8];   // tt 0..3 = K-side (d = tt*16+c16), 4..7 = V-side
    #pragma unroll
    for (int mt = 0; mt < G_; ++mt)
      #pragma unroll
      for (int tt = 0; tt < 8; ++tt) acc2[mt][tt] = zero4;

    for (int ks = 0; ks < 16; ++ks) {
      bf16x8 a[G_];
      #pragma unroll
      for (int mt = 0; mt < G_; ++mt)
        a[mt] = *(const bf16x8*)&s_a[((mt * 16 + ks) * 64 + lane) * 8];
      // batched B-frag loads
      bf16x8 bfr[8];
      #pragma unroll
      for (int tt = 0; tt < 8; ++tt)
        bfr[tt] = *(const bf16x8*)&W2f[((size_t)((h * 8 + tt) * 16 + ks) * 64 + lane) * 8];
      #pragma unroll
      for (int tt = 0; tt < 8; ++tt)
        #pragma unroll
        for (int mt = 0; mt < G_; ++mt)
          acc2[mt][tt] = __builtin_amdgcn_mfma_f32_16x16x32_bf16(a[mt], bfr[tt], acc2[mt][tt], 0, 0, 0);
    }

    // epilogue for head h (all f32). C layout: col = c16, row m = g*4 + reg.
    float b2k[4], b2v[4], qv[G_][4];
    #pragma unroll
    for (int tt = 0; tt < 4; ++tt) {
      b2k[tt] = b2[h * 128 + tt * 16 + c16];
      b2v[tt] = b2[h * 128 + 64 + tt * 16 + c16];
    }
    #pragma unroll
    for (int mt = 0; mt < G_; ++mt)
      #pragma unroll
      for (int tt = 0; tt < 4; ++tt)
        qv[mt][tt] = qh[(size_t)(bi0 + mt) * DH + h * 64 + tt * 16 + c16];

    #pragma unroll
    for (int mt = 0; mt < G_; ++mt) {
      float pj[4];
      #pragma unroll
      for (int r = 0; r < 4; ++r) {
        const float* kvrow = kv + ((size_t)b * NK_ + idxr[mt][r]) * (2 * DH);
        float s = 0.f;
        #pragma unroll
        for (int tt = 0; tt < 4; ++tt) {
          const int d = h * 64 + tt * 16 + c16;
          const float kg = acc2[mt][tt][r] + b2k[tt] + kvrow[d];
          s += qv[mt][tt] * kg;
          acc2[mt][4 + tt][r] += b2v[tt] + kvrow[DH + d];   // vg in place
        }
        s += __shfl_xor(s, 1);  s += __shfl_xor(s, 2);
        s += __shfl_xor(s, 4);  s += __shfl_xor(s, 8);      // full q.kg
        pj[r] = s * 0.125f;                                  // D_K^-0.5
      }
      // softmax over the 16 j (j = g*4 + r): cross-group via xor 16/32
      float mx = fmaxf(fmaxf(pj[0], pj[1]), fmaxf(pj[2], pj[3]));
      mx = fmaxf(mx, __shfl_xor(mx, 16));
      mx = fmaxf(mx, __shfl_xor(mx, 32));
      float sum = 0.f;
      #pragma unroll
      for (int r = 0; r < 4; ++r) { pj[r] = __expf(pj[r] - mx); sum += pj[r]; }
      sum += __shfl_xor(sum, 16);
      sum += __shfl_xor(sum, 32);
      const float inv = 1.f / sum;
      #pragma unroll
      for (int r = 0; r < 4; ++r) pj[r] *= inv;
      // V aggregation; xor 16/32 sums over all j groups; write straight to
      // s_agg2 (separate buffer -- no conflict with s_a readers in other waves)
      #pragma unroll
      for (int tt = 0; tt < 4; ++tt) {
        float a_ = pj[0] * acc2[mt][4 + tt][0] + pj[1] * acc2[mt][4 + tt][1]
                 + pj[2] * acc2[mt][4 + tt][2] + pj[3] * acc2[mt][4 + tt][3];
        a_ += __shfl_xor(a_, 16);
        a_ += __shfl_xor(a_, 32);
        if (g == 0)
          s_agg2[mt * DH + h * 64 + tt * 16 + c16] = a_;
      }
    }
  }
  __syncthreads();   // s_agg2 complete; all waves done reading s_a

  // ---- out = agg @ Wout; wave w sums k-range [w*128, w*128+128) ----
  float* s_part = (float*)s_a;   // 16 KB overlay, pos/hidden frags dead now
  f32x4 oacc[G_];
  #pragma unroll
  for (int i = 0; i < G_; ++i) oacc[i] = zero4;
  for (int c4 = 0; c4 < 32; ++c4) {
    const int c = w * 128 + c4 * 4;
    f32x4 ag[G_];
    #pragma unroll
    for (int i = 0; i < G_; ++i) ag[i] = *(const f32x4*)&s_agg2[i * DH + c];
    #pragma unroll
    for (int cc = 0; cc < 4; ++cc) {
      const f32x4 wv = *(const f32x4*)&Wout[(size_t)(c + cc) * DM + lane * 4];
      #pragma unroll
      for (int i = 0; i < G_; ++i) oacc[i] += wv * ag[i][cc];
    }
  }
  #pragma unroll
  for (int i = 0; i < G_; ++i)
    *(f32x4*)&s_part[(w * G_ + i) * DM + lane * 4] = oacc[i];
  __syncthreads();

  #pragma unroll
  for (int i = 0; i < G_; ++i) {
    const float o = s_part[(0 * G_ + i) * DM + t] + s_part[(1 * G_ + i) * DM + t]
                  + s_part[(2 * G_ + i) * DM + t] + s_part[(3 * G_ + i) * DM + t];
    out[(size_t)(bi0 + i) * DM + t] = o;
  }
}

// ---------------------------------------------------------------------------
extern "C" void kernel_launch(void* const* d_in, const int* in_sizes, int n_in,
                              void* d_out, int out_size, void* d_ws, size_t ws_size,
                              hipStream_t stream)
{
  const float* q    = (const float*)d_in[0];
  const float* k    = (const float*)d_in[1];
  const float* pos  = (const float*)d_in[2];
  const int*   lidx = (const int*)d_in[3];
  const float* Wq   = (const float*)d_in[4];
  const float* Wkv  = (const float*)d_in[5];
  const float* W1   = (const float*)d_in[6];
  const float* b1   = (const float*)d_in[7];
  const float* W2   = (const float*)d_in[8];
  const float* b2   = (const float*)d_in[9];
  const float* Wout = (const float*)d_in[10];
  float* out = (float*)d_out;

  // ws: qh 8MB | kv 16MB | W1f 512KB | W2f 1MB | Wqf 256KB | Wkvf 512KB
  float* qh_ws = (float*)d_ws;
  float* kv_ws = qh_ws + (size_t)(B_ * I_) * DH;
  unsigned short* W1f  = (unsigned short*)(kv_ws + (size_t)(B_ * NK_) * (2 * DH));
  unsigned short* W2f  = W1f + (size_t)DH * DH;
  unsigned short* Wqf  = W2f + (size_t)DH * (2 * DH);
  unsigned short* Wkvf = Wqf + (size_t)DM * DH;

  swz_kernel<<<576, 256, 0, stream>>>(Wq, Wkv, W1, W2, Wqf, Wkvf, W1f, W2f);
  proj_mfma<<<128, 256, 0, stream>>>(q, k, Wqf, Wkvf, qh_ws, kv_ws);
  fused_mfma<<<(B_ * I_) / G_, 256, 0, stream>>>(pos, lidx, qh_ws, kv_ws,
                                                 W1f, b1, W2f, b2, Wout, out);
}

// Round 9
// 353.529 us; speedup vs baseline: 1.3871x; 1.1134x over previous
//
#include <hip/hip_runtime.h>
#include <hip/hip_bf16.h>
#include <cstddef>

// MultiHeadedCrossAttention, Round 13.
// B=2, I=2048, J=16, NK=2048, D_MODEL=256, D_HIDDEN=512, H=8, D_K=64.
//
// R12 bisect verdict: the K/V-split (64-f32 accumulator arrays through a
// runtime ks-loop) corrupts even in full isolation (R9/R11/R12 all ~1.5e-2;
// R6's failing config was also 64-f32 acc). Source-invisible -> codegen
// pathology. Direction CLOSED. All accumulator arrays stay 128-f32 and the
// monolithic fused skeleton stays.
// R13 = R10-verbatim + s_setprio(1) around MFMA clusters (T5). Fused runs
// 2 independent blocks/CU (not barrier-locked against each other) -> the
// phase-diverse regime where setprio helps. Scheduler hint: zero semantic
// risk, guaranteed re-anchor.

#define B_  2
#define I_  2048
#define J_  16
#define NK_ 2048
#define DM  256
#define DH  512
#define H_  8
#define DK  64
#define G_  4    // i's per fused block

typedef __attribute__((ext_vector_type(8))) __bf16 bf16x8;
typedef __attribute__((ext_vector_type(4))) float f32x4;
typedef __attribute__((ext_vector_type(8))) unsigned short ushort8;

__device__ inline unsigned short f2bf(float f) {   // RNE float->bf16
  unsigned int u = __builtin_bit_cast(unsigned int, f);
  u += 0x7FFFu + ((u >> 16) & 1u);
  return (unsigned short)(u >> 16);
}

// 8x f32 -> bf16x8 via native converts (v_cvt_pk_bf16_f32, RNE == f2bf).
__device__ inline bf16x8 cvt8(float4 a, float4 b) {
  bf16x8 r;
  r[0] = (__bf16)a.x; r[1] = (__bf16)a.y; r[2] = (__bf16)a.z; r[3] = (__bf16)a.w;
  r[4] = (__bf16)b.x; r[5] = (__bf16)b.y; r[6] = (__bf16)b.z; r[7] = (__bf16)b.w;
  return r;
}

// ---------------------------------------------------------------------------
// Weight pre-swizzle (R10-verbatim): W (K x N f32) -> bf16 B-frags.
// Frag (nt, ks): lane l holds B[k = ks*32 + (l>>4)*8 + j][n = nt*16 + (l&15)],
// j=0..7, 16B-contiguous at Wf[((nt*KS + ks)*64 + l)*8].  KS = K/32.
// ---------------------------------------------------------------------------
template<int N, int KS>
__device__ void swz_body(const float* __restrict__ W,
                         unsigned short* __restrict__ Wf, int bid, int t)
{
  const int u  = bid * 256 + t;
  const int l  = u & 63;
  const int fi = u >> 6;
  const int ks = fi % KS;
  const int nt = fi / KS;
  const int n  = nt * 16 + (l & 15);
  const int k0 = ks * 32 + (l >> 4) * 8;
  unsigned short tmp[8];
  #pragma unroll
  for (int j = 0; j < 8; ++j) tmp[j] = f2bf(W[(size_t)(k0 + j) * N + n]);
  *(ushort8*)&Wf[(size_t)u * 8] = *(const ushort8*)tmp;
}

__global__ __launch_bounds__(256) void swz_kernel(
    const float* __restrict__ Wq, const float* __restrict__ Wkv,
    const float* __restrict__ W1, const float* __restrict__ W2,
    unsigned short* __restrict__ Wqf, unsigned short* __restrict__ Wkvf,
    unsigned short* __restrict__ W1f, unsigned short* __restrict__ W2f)
{
  const int bid = blockIdx.x;
  const int t = threadIdx.x;
  if (bid < 64)        swz_body<DH, 8>    (Wq,  Wqf,  bid,       t);
  else if (bid < 192)  swz_body<2*DH, 8>  (Wkv, Wkvf, bid - 64,  t);
  else if (bid < 320)  swz_body<DH, 16>   (W1,  W1f,  bid - 192, t);
  else                 swz_body<2*DH, 16> (W2,  W2f,  bid - 320, t);
}

// ---------------------------------------------------------------------------
// MFMA projections (R10-verbatim + setprio): qh = q @ Wq, kv = k @ Wkv.
// ---------------------------------------------------------------------------
__global__ __launch_bounds__(256) void proj_mfma(
    const float* __restrict__ q, const float* __restrict__ k,
    const unsigned short* __restrict__ Wqf,
    const unsigned short* __restrict__ Wkvf,
    float* __restrict__ qh_ws, float* __restrict__ kv_ws)
{
  const int t    = threadIdx.x;
  const int lane = t & 63;
  const int w    = t >> 6;
  const int g    = lane >> 4;
  const int c16  = lane & 15;

  const bool is_kv = blockIdx.x >= 64;
  const int  bid   = is_kv ? (int)blockIdx.x - 64 : (int)blockIdx.x;
  const int  row0  = bid * 64;
  const float* X = is_kv ? k : q;
  const unsigned short* Wf = is_kv ? Wkvf : Wqf;
  const int  N     = is_kv ? 2 * DH : DH;
  float*     Y     = is_kv ? kv_ws : qh_ws;
  const int  passes = is_kv ? 2 : 1;

  const f32x4 zero4 = {0.f, 0.f, 0.f, 0.f};
  const float* pa = X + (size_t)(row0 + (lane & 15)) * DM + ((lane >> 4) << 3);

  for (int hp = 0; hp < passes; ++hp) {
    f32x4 acc[G_][8];
    #pragma unroll
    for (int mt = 0; mt < G_; ++mt)
      #pragma unroll
      for (int nt = 0; nt < 8; ++nt) acc[mt][nt] = zero4;

    for (int ks = 0; ks < 8; ++ks) {          // K = 256 -> 8 steps
      bf16x8 a[G_];
      #pragma unroll
      for (int mt = 0; mt < G_; ++mt) {
        const float* s = pa + (size_t)mt * 16 * DM + ks * 32;
        a[mt] = cvt8(*(const float4*)s, *(const float4*)(s + 4));
      }
      bf16x8 bfr[8];
      #pragma unroll
      for (int nt = 0; nt < 8; ++nt) {
        const int ntg = hp * 32 + w * 8 + nt;
        bfr[nt] = *(const bf16x8*)&Wf[((size_t)(ntg * 8 + ks) * 64 + lane) * 8];
      }
      __builtin_amdgcn_s_setprio(1);
      #pragma unroll
      for (int nt = 0; nt < 8; ++nt)
        #pragma unroll
        for (int mt = 0; mt < G_; ++mt)
          acc[mt][nt] = __builtin_amdgcn_mfma_f32_16x16x32_bf16(a[mt], bfr[nt], acc[mt][nt], 0, 0, 0);
      __builtin_amdgcn_s_setprio(0);
    }

    #pragma unroll
    for (int nt = 0; nt < 8; ++nt) {
      const int col = hp * 512 + (w * 8 + nt) * 16 + c16;
      #pragma unroll
      for (int mt = 0; mt < G_; ++mt)
        #pragma unroll
        for (int r = 0; r < 4; ++r)
          Y[(size_t)(row0 + mt * 16 + g * 4 + r) * N + col] = acc[mt][nt][r];
    }
  }
}

// ---------------------------------------------------------------------------
// K3: fused MFMA pos-MLP + gather + attention + out-projection.
// R10-VERBATIM skeleton + setprio around MFMA clusters.
// ---------------------------------------------------------------------------
__global__ __launch_bounds__(256, 2) void fused_mfma(
    const float* __restrict__ pos, const int* __restrict__ lidx,
    const float* __restrict__ qh, const float* __restrict__ kv,
    const unsigned short* __restrict__ W1f, const float* __restrict__ b1,
    const unsigned short* __restrict__ W2f, const float* __restrict__ b2,
    const float* __restrict__ Wout, float* __restrict__ out)
{
  __shared__ unsigned short s_a[G_ * 16 * 64 * 8];   // 64 KB: pos frags -> hidden frags -> s_part
  __shared__ float s_agg2[G_ * DH];                  // 8 KB: attention output

  const int t    = threadIdx.x;
  const int lane = t & 63;
  const int w    = t >> 6;        // wave 0..3
  const int g    = lane >> 4;     // row-group within C layout
  const int c16  = lane & 15;     // col within 16-tile
  const int bi0  = blockIdx.x * G_;
  const int b    = bi0 >> 11;     // / I_

  // local_idx may be int64 (reference) or int32; detect (values < 2048 so
  // int64 high words are all zero).
  bool idx64;
  {
    int orv = 0;
    #pragma unroll
    for (int m = 0; m < 16; ++m) orv |= lidx[2 * m + 1];
    idx64 = (orv == 0);
  }
  // gather indices this lane needs: j = g*4 + r for each i (=m-tile)
  int idxr[G_][4];
  #pragma unroll
  for (int mt = 0; mt < G_; ++mt)
    #pragma unroll
    for (int r = 0; r < 4; ++r) {
      const int e = (bi0 + mt) * J_ + g * 4 + r;
      idxr[mt][r] = idx64 ? lidx[2 * e] : lidx[e];
    }

  // ---- stage pos (64 rows x 512 cols) -> s_a in A-frag order (bf16) ----
  #pragma unroll
  for (int it = 0; it < 16; ++it) {
    const int u  = t + it * 256;
    const int fi = u >> 6, ld = u & 63;
    const int mt = fi >> 4, ks = fi & 15;
    const int row = mt * 16 + (ld & 15);
    const int col = ks * 32 + (ld >> 4) * 8;
    const float* src = pos + (size_t)(bi0 * J_ + row) * DH + col;
    const float4 v0 = *(const float4*)src;
    const float4 v1 = *(const float4*)(src + 4);
    unsigned short tmp[8];
    tmp[0] = f2bf(v0.x); tmp[1] = f2bf(v0.y); tmp[2] = f2bf(v0.z); tmp[3] = f2bf(v0.w);
    tmp[4] = f2bf(v1.x); tmp[5] = f2bf(v1.y); tmp[6] = f2bf(v1.z); tmp[7] = f2bf(v1.w);
    *(ushort8*)&s_a[(size_t)u * 8] = *(const ushort8*)tmp;
  }
  __syncthreads();

  const f32x4 zero4 = {0.f, 0.f, 0.f, 0.f};

  // ---- stage 1: hidden = relu(pos @ W1 + b1); wave w owns cols w*128.. ----
  f32x4 acc1[G_][8];
  #pragma unroll
  for (int mt = 0; mt < G_; ++mt)
    #pragma unroll
    for (int nt = 0; nt < 8; ++nt) acc1[mt][nt] = zero4;

  for (int ks = 0; ks < 16; ++ks) {
    bf16x8 a[G_];
    #pragma unroll
    for (int mt = 0; mt < G_; ++mt)
      a[mt] = *(const bf16x8*)&s_a[((mt * 16 + ks) * 64 + lane) * 8];
    // batched B-frag loads: all 8 in flight before the MFMA cluster
    bf16x8 bfr[8];
    #pragma unroll
    for (int nt = 0; nt < 8; ++nt)
      bfr[nt] = *(const bf16x8*)&W1f[((size_t)((w * 8 + nt) * 16 + ks) * 64 + lane) * 8];
    __builtin_amdgcn_s_setprio(1);
    #pragma unroll
    for (int nt = 0; nt < 8; ++nt)
      #pragma unroll
      for (int mt = 0; mt < G_; ++mt)
        acc1[mt][nt] = __builtin_amdgcn_mfma_f32_16x16x32_bf16(a[mt], bfr[nt], acc1[mt][nt], 0, 0, 0);
    __builtin_amdgcn_s_setprio(0);
  }
  __syncthreads();   // everyone done reading pos frags

  // ---- relu + b1, scatter into s_a as stage-2 A-frags ----
  #pragma unroll
  for (int nt = 0; nt < 8; ++nt) {
    const int col  = (w * 8 + nt) * 16 + c16;
    const float bb = b1[col];
    const int ks2  = col >> 5;
    const int lsel = ((col >> 3) & 3) * 16;
    const int bj   = col & 7;
    #pragma unroll
    for (int mt = 0; mt < G_; ++mt)
      #pragma unroll
      for (int r = 0; r < 4; ++r) {
        const float hv = fmaxf(acc1[mt][nt][r] + bb, 0.f);
        s_a[((mt * 16 + ks2) * 64 + (g * 4 + r) + lsel) * 8 + bj] = f2bf(hv);
      }
  }
  __syncthreads();

  // ---- stage 2 + attention: one head per pass; wave w -> heads 2w, 2w+1 ----
  #pragma unroll
  for (int p = 0; p < 2; ++p) {
    const int h = 2 * w + p;
    f32x4 acc2[G_][8];   // tt 0..3 = K-side (d = tt*16+c16), 4..7 = V-side
    #pragma unroll
    for (int mt = 0; mt < G_; ++mt)
      #pragma unroll
      for (int tt = 0; tt < 8; ++tt) acc2[mt][tt] = zero4;

    for (int ks = 0; ks < 16; ++ks) {
      bf16x8 a[G_];
      #pragma unroll
      for (int mt = 0; mt < G_; ++mt)
        a[mt] = *(const bf16x8*)&s_a[((mt * 16 + ks) * 64 + lane) * 8];
      // batched B-frag loads
      bf16x8 bfr[8];
      #pragma unroll
      for (int tt = 0; tt < 8; ++tt)
        bfr[tt] = *(const bf16x8*)&W2f[((size_t)((h * 8 + tt) * 16 + ks) * 64 + lane) * 8];
      __builtin_amdgcn_s_setprio(1);
      #pragma unroll
      for (int tt = 0; tt < 8; ++tt)
        #pragma unroll
        for (int mt = 0; mt < G_; ++mt)
          acc2[mt][tt] = __builtin_amdgcn_mfma_f32_16x16x32_bf16(a[mt], bfr[tt], acc2[mt][tt], 0, 0, 0);
      __builtin_amdgcn_s_setprio(0);
    }

    // epilogue for head h (all f32). C layout: col = c16, row m = g*4 + reg.
    float b2k[4], b2v[4], qv[G_][4];
    #pragma unroll
    for (int tt = 0; tt < 4; ++tt) {
      b2k[tt] = b2[h * 128 + tt * 16 + c16];
      b2v[tt] = b2[h * 128 + 64 + tt * 16 + c16];
    }
    #pragma unroll
    for (int mt = 0; mt < G_; ++mt)
      #pragma unroll
      for (int tt = 0; tt < 4; ++tt)
        qv[mt][tt] = qh[(size_t)(bi0 + mt) * DH + h * 64 + tt * 16 + c16];

    #pragma unroll
    for (int mt = 0; mt < G_; ++mt) {
      float pj[4];
      #pragma unroll
      for (int r = 0; r < 4; ++r) {
        const float* kvrow = kv + ((size_t)b * NK_ + idxr[mt][r]) * (2 * DH);
        float s = 0.f;
        #pragma unroll
        for (int tt = 0; tt < 4; ++tt) {
          const int d = h * 64 + tt * 16 + c16;
          const float kg = acc2[mt][tt][r] + b2k[tt] + kvrow[d];
          s += qv[mt][tt] * kg;
          acc2[mt][4 + tt][r] += b2v[tt] + kvrow[DH + d];   // vg in place
        }
        s += __shfl_xor(s, 1);  s += __shfl_xor(s, 2);
        s += __shfl_xor(s, 4);  s += __shfl_xor(s, 8);      // full q.kg
        pj[r] = s * 0.125f;                                  // D_K^-0.5
      }
      // softmax over the 16 j (j = g*4 + r): cross-group via xor 16/32
      float mx = fmaxf(fmaxf(pj[0], pj[1]), fmaxf(pj[2], pj[3]));
      mx = fmaxf(mx, __shfl_xor(mx, 16));
      mx = fmaxf(mx, __shfl_xor(mx, 32));
      float sum = 0.f;
      #pragma unroll
      for (int r = 0; r < 4; ++r) { pj[r] = __expf(pj[r] - mx); sum += pj[r]; }
      sum += __shfl_xor(sum, 16);
      sum += __shfl_xor(sum, 32);
      const float inv = 1.f / sum;
      #pragma unroll
      for (int r = 0; r < 4; ++r) pj[r] *= inv;
      // V aggregation; xor 16/32 sums over all j groups; write straight to
      // s_agg2 (separate buffer -- no conflict with s_a readers in other waves)
      #pragma unroll
      for (int tt = 0; tt < 4; ++tt) {
        float a_ = pj[0] * acc2[mt][4 + tt][0] + pj[1] * acc2[mt][4 + tt][1]
                 + pj[2] * acc2[mt][4 + tt][2] + pj[3] * acc2[mt][4 + tt][3];
        a_ += __shfl_xor(a_, 16);
        a_ += __shfl_xor(a_, 32);
        if (g == 0)
          s_agg2[mt * DH + h * 64 + tt * 16 + c16] = a_;
      }
    }
  }
  __syncthreads();   // s_agg2 complete; all waves done reading s_a

  // ---- out = agg @ Wout; wave w sums k-range [w*128, w*128+128) ----
  float* s_part = (float*)s_a;   // 16 KB overlay, pos/hidden frags dead now
  f32x4 oacc[G_];
  #pragma unroll
  for (int i = 0; i < G_; ++i) oacc[i] = zero4;
  for (int c4 = 0; c4 < 32; ++c4) {
    const int c = w * 128 + c4 * 4;
    f32x4 ag[G_];
    #pragma unroll
    for (int i = 0; i < G_; ++i) ag[i] = *(const f32x4*)&s_agg2[i * DH + c];
    #pragma unroll
    for (int cc = 0; cc < 4; ++cc) {
      const f32x4 wv = *(const f32x4*)&Wout[(size_t)(c + cc) * DM + lane * 4];
      #pragma unroll
      for (int i = 0; i < G_; ++i) oacc[i] += wv * ag[i][cc];
    }
  }
  #pragma unroll
  for (int i = 0; i < G_; ++i)
    *(f32x4*)&s_part[(w * G_ + i) * DM + lane * 4] = oacc[i];
  __syncthreads();

  #pragma unroll
  for (int i = 0; i < G_; ++i) {
    const float o = s_part[(0 * G_ + i) * DM + t] + s_part[(1 * G_ + i) * DM + t]
                  + s_part[(2 * G_ + i) * DM + t] + s_part[(3 * G_ + i) * DM + t];
    out[(size_t)(bi0 + i) * DM + t] = o;
  }
}

// ---------------------------------------------------------------------------
extern "C" void kernel_launch(void* const* d_in, const int* in_sizes, int n_in,
                              void* d_out, int out_size, void* d_ws, size_t ws_size,
                              hipStream_t stream)
{
  const float* q    = (const float*)d_in[0];
  const float* k    = (const float*)d_in[1];
  const float* pos  = (const float*)d_in[2];
  const int*   lidx = (const int*)d_in[3];
  const float* Wq   = (const float*)d_in[4];
  const float* Wkv  = (const float*)d_in[5];
  const float* W1   = (const float*)d_in[6];
  const float* b1   = (const float*)d_in[7];
  const float* W2   = (const float*)d_in[8];
  const float* b2   = (const float*)d_in[9];
  const float* Wout = (const float*)d_in[10];
  float* out = (float*)d_out;

  // ws: qh 8MB | kv 16MB | W1f 512KB | W2f 1MB | Wqf 256KB | Wkvf 512KB
  float* qh_ws = (float*)d_ws;
  float* kv_ws = qh_ws + (size_t)(B_ * I_) * DH;
  unsigned short* W1f  = (unsigned short*)(kv_ws + (size_t)(B_ * NK_) * (2 * DH));
  unsigned short* W2f  = W1f + (size_t)DH * DH;
  unsigned short* Wqf  = W2f + (size_t)DH * (2 * DH);
  unsigned short* Wkvf = Wqf + (size_t)DM * DH;

  swz_kernel<<<576, 256, 0, stream>>>(Wq, Wkv, W1, W2, Wqf, Wkvf, W1f, W2f);
  proj_mfma<<<128, 256, 0, stream>>>(q, k, Wqf, Wkvf, qh_ws, kv_ws);
  fused_mfma<<<(B_ * I_) / G_, 256, 0, stream>>>(pos, lidx, qh_ws, kv_ws,
                                                 W1f, b1, W2f, b2, Wout, out);
}